// Round 5
// baseline (782.477 us; speedup 1.0000x reference)
//
#include <hip/hip_runtime.h>

typedef unsigned short u16;
typedef __attribute__((ext_vector_type(8))) short short8;
typedef __attribute__((ext_vector_type(4))) float floatx4;

#define NN 50000
#define NE 1600000
#define BN_EPS 1e-5f
#define NSCAN 196             // ceil(NN/256)
#define TPB 4                 // 16-edge tiles per k_edge5 block

__device__ __forceinline__ float bfu(u16 u) {
    union { unsigned u32; float f; } v; v.u32 = ((unsigned)u) << 16; return v.f;
}
__device__ __forceinline__ u16 f2bf(float f) {
    union { float f; unsigned u; } v; v.f = f;
    unsigned r = v.u + 0x7FFFu + ((v.u >> 16) & 1u);
    return (u16)(r >> 16);
}
// mode m: 1 = buffers hold float32, 0 = buffers hold bf16
__device__ __forceinline__ float ldf(const void* p, int i, int m) {
    return m ? ((const float*)p)[i] : bfu(((const u16*)p)[i]);
}

// K0b: canonicalize all MFMA-consumed weights to bf16 ws copies, with INLINE dtype
// detection (each block recomputes mode from x; block 0 publishes it for later kernels).
// Layout in dst: Wfe0[16384] | We1[8192] | Wfn0[16384] | Wn1[8192] | Wfn1[16384]
__global__ __launch_bounds__(256) void k_cvtw(const u16* __restrict__ x,
                                              const void* __restrict__ W0, const void* __restrict__ W1,
                                              const void* __restrict__ W2, const void* __restrict__ W3,
                                              const void* __restrict__ W4,
                                              u16* __restrict__ dst, int* __restrict__ mode) {
    int t = threadIdx.x;
    __shared__ float sred[4];
    float mx = 0.f;
    for (int i = t; i < 4096; i += 256) mx = fmaxf(mx, fabsf(bfu(x[i])));
#pragma unroll
    for (int o = 32; o > 0; o >>= 1) mx = fmaxf(mx, __shfl_down(mx, o));
    if ((t & 63) == 0) sred[t >> 6] = mx;
    __syncthreads();
    float m2 = fmaxf(fmaxf(sred[0], sred[1]), fmaxf(sred[2], sred[3]));
    int m = (m2 > 1e4f) ? 1 : 0;
    if (blockIdx.x == 0 && t == 0) mode[0] = m;
    int i = blockIdx.x * 256 + t;   // 65536 total
    const void* src; int off;
    if (i < 16384)      { src = W0; off = i; }
    else if (i < 24576) { src = W1; off = i - 16384; }
    else if (i < 40960) { src = W2; off = i - 24576; }
    else if (i < 49152) { src = W3; off = i - 40960; }
    else                { src = W4; off = i - 49152; }
    dst[i] = m ? f2bf(((const float*)src)[off]) : ((const u16*)src)[off];
}

// K1h: fused {node encoder l0 (16 nodes/block)} + {dst-degree histogram} via block-range split.
__global__ __launch_bounds__(256) void k_enc0h(const void* __restrict__ x, const void* __restrict__ Wn,
                                               u16* __restrict__ n1, const int* __restrict__ ei,
                                               int* __restrict__ cnt, const int* __restrict__ mf) {
    int b = blockIdx.x;
    int t = threadIdx.x;
    if (b >= 3125) {   // histogram part: 6250 blocks
        int e = (b - 3125) * 256 + t;
        atomicAdd(cnt + ei[NE + e], 1);
        return;
    }
    int m = mf[0];
    __shared__ float Wns[64 * 17];
    __shared__ float xsh[16][17];
    int n0 = b * 16;
    for (int i = t; i < 1024; i += 256) Wns[(i >> 4) * 17 + (i & 15)] = ldf(Wn, i, m);
    xsh[t >> 4][t & 15] = ldf(x, n0 * 16 + t, m);
    __syncthreads();
    int c = t & 63, ng = t >> 6;   // ng: node group 0..3, nodes ng*4..ng*4+3
    float a0 = 0.f, a1 = 0.f, a2 = 0.f, a3 = 0.f;
#pragma unroll
    for (int k = 0; k < 16; k++) {
        float wv = Wns[c * 17 + k];
        a0 += xsh[ng * 4 + 0][k] * wv;
        a1 += xsh[ng * 4 + 1][k] * wv;
        a2 += xsh[ng * 4 + 2][k] * wv;
        a3 += xsh[ng * 4 + 3][k] * wv;
    }
    n1[(n0 + ng * 4 + 0) * 64 + c] = f2bf(fmaxf(a0, 0.f));
    n1[(n0 + ng * 4 + 1) * 64 + c] = f2bf(fmaxf(a1, 0.f));
    n1[(n0 + ng * 4 + 2) * 64 + c] = f2bf(fmaxf(a2, 0.f));
    n1[(n0 + ng * 4 + 3) * 64 + c] = f2bf(fmaxf(a3, 0.f));
}

// Scan phase 1: per-256-block sums of cnt
__global__ __launch_bounds__(256) void k_scan1(const int* __restrict__ cnt, int* __restrict__ bsum) {
    int t = threadIdx.x;
    int idx = blockIdx.x * 256 + t;
    int v = (idx < NN) ? cnt[idx] : 0;
#pragma unroll
    for (int o = 32; o > 0; o >>= 1) v += __shfl_down(v, o);
    __shared__ int s[4];
    if ((t & 63) == 0) s[t >> 6] = v;
    __syncthreads();
    if (t == 0) bsum[blockIdx.x] = s[0] + s[1] + s[2] + s[3];
}

// Scan phase 2 + K_PN fold (both tiny single-block jobs).
__global__ __launch_bounds__(256) void k_scan2pn(int* __restrict__ bsum,
                                                 const void* __restrict__ We0, const void* __restrict__ Wfe0,
                                                 float* __restrict__ PN, const int* __restrict__ mf) {
    __shared__ int sh[256];
    int t = threadIdx.x;
    int v = (t < NSCAN) ? bsum[t] : 0;
    sh[t] = v;
    __syncthreads();
    for (int o = 1; o < 256; o <<= 1) {
        int u = (t >= o) ? sh[t - o] : 0;
        __syncthreads();
        sh[t] += u;
        __syncthreads();
    }
    if (t < NSCAN) bsum[t] = sh[t] - v;   // exclusive
    if (t < 128) {
        int m = mf[0];
        float p = 0.f, n = 0.f;
        for (int k = 0; k < 64; k++) {
            float w = ldf(We0, k, m);
            float wf = ldf(Wfe0, t * 128 + 64 + k, m);
            p += fmaxf(w, 0.f) * wf;
            n += fminf(w, 0.f) * wf;
        }
        PN[t] = p; PN[128 + t] = n;
    }
}

// Scan phase 3: per-block exclusive scan + offset -> cursor[] (scatter cursors)
__global__ __launch_bounds__(256) void k_scan3(const int* __restrict__ cnt, const int* __restrict__ bsum,
                                               int* __restrict__ cursor) {
    __shared__ int sh[256];
    int t = threadIdx.x;
    int idx = blockIdx.x * 256 + t;
    int v = (idx < NN) ? cnt[idx] : 0;
    sh[t] = v;
    __syncthreads();
    for (int o = 1; o < 256; o <<= 1) {
        int u = (t >= o) ? sh[t - o] : 0;
        __syncthreads();
        sh[t] += u;
        __syncthreads();
    }
    int excl = sh[t] - v + bsum[blockIdx.x];
    if (idx < NN) cursor[idx] = excl;
}

// Scatter: one packed 8B record per edge into its dst-sorted slot; also the
// per-node positive/negative edge_attr sums (moved here from the old k_esum).
__global__ __launch_bounds__(256) void k_scatter(const void* __restrict__ ea, const int* __restrict__ ei,
                                                 int* __restrict__ cursor, int2* __restrict__ edata,
                                                 float* __restrict__ sp, float* __restrict__ sn,
                                                 const int* __restrict__ mf) {
    int m = mf[0];
    int e = blockIdx.x * 256 + threadIdx.x;
    int d = ei[NE + e];
    int s = ei[e];
    float a = ldf(ea, e, m);
    int p = atomicAdd(cursor + d, 1);
    int2 v;
    v.x = (int)((unsigned)s | ((unsigned)d << 16));
    v.y = __float_as_int(a);
    edata[p] = v;
    if (a > 0.f) atomicAdd(sp + d, a);
    else if (a < 0.f) atomicAdd(sn + d, a);
}

// K34: fused node MLP l0 + BN + node encoder l1 -> n1_l1 [50000 x 64] bf16. MFMA, 64 nodes/block.
__global__ __launch_bounds__(256) void k_node_l0(
    const u16* __restrict__ n1l0, const float* __restrict__ sp, const float* __restrict__ sn,
    const void* __restrict__ We0, const u16* __restrict__ Wfn0c, const void* __restrict__ bfn0,
    const void* __restrict__ g0, const void* __restrict__ b0,
    const void* __restrict__ rm0, const void* __restrict__ rv0,
    const u16* __restrict__ Wn1c, u16* __restrict__ n1l1, const int* __restrict__ mf) {
    int m = mf[0];
    __shared__ __align__(16) u16 fs[64][136];
    __shared__ __align__(16) u16 xs[64][136];
    int t = threadIdx.x;
    int n0 = blockIdx.x * 64;
    {   // fs[row][col] = concat(analytic agg_l0, n1_l0), bf16
        int col = t & 127;
        int rbase = t >> 7;              // 0 or 1
        float wp = 0.f, wn = 0.f;
        if (col < 64) { float w0 = ldf(We0, col, m); wp = fmaxf(w0, 0.f); wn = fminf(w0, 0.f); }
#pragma unroll
        for (int i = 0; i < 32; i++) {
            int row = rbase + 2 * i;
            int n = n0 + row;
            float v = 0.f;
            if (n < NN) v = (col < 64) ? (wp * sp[n] + wn * sn[n]) : bfu(n1l0[n * 64 + col - 64]);
            fs[row][col] = f2bf(v);
        }
    }
    __syncthreads();
    int lane = t & 63, w = t >> 6, q = lane >> 4, nidx = lane & 15;
    {
        const u16* ar = &fs[w * 16 + nidx][0];
        short8 a0 = *(const short8*)&ar[q * 8];
        short8 a1 = *(const short8*)&ar[32 + q * 8];
        short8 a2 = *(const short8*)&ar[64 + q * 8];
        short8 a3 = *(const short8*)&ar[96 + q * 8];
#pragma unroll
        for (int jt = 0; jt < 8; jt++) {
            int j = jt * 16 + nidx;
            const u16* wr = Wfn0c + j * 128;
            floatx4 acc = {0.f, 0.f, 0.f, 0.f};
            acc = __builtin_amdgcn_mfma_f32_16x16x32_bf16(a0, *(const short8*)&wr[q * 8], acc, 0, 0, 0);
            acc = __builtin_amdgcn_mfma_f32_16x16x32_bf16(a1, *(const short8*)&wr[32 + q * 8], acc, 0, 0, 0);
            acc = __builtin_amdgcn_mfma_f32_16x16x32_bf16(a2, *(const short8*)&wr[64 + q * 8], acc, 0, 0, 0);
            acc = __builtin_amdgcn_mfma_f32_16x16x32_bf16(a3, *(const short8*)&wr[96 + q * 8], acc, 0, 0, 0);
            float bias = ldf(bfn0, j, m);
            float sc = ldf(g0, j, m) * rsqrtf(ldf(rv0, j, m) + BN_EPS);
            float sh = ldf(b0, j, m) - ldf(rm0, j, m) * sc;
#pragma unroll
            for (int r = 0; r < 4; r++) {
                int row = w * 16 + q * 4 + r;
                xs[row][j] = f2bf(fmaxf(acc[r] + bias, 0.f) * sc + sh);
            }
        }
    }
    __syncthreads();
    {
        const u16* ar = &xs[w * 16 + nidx][0];
        short8 a0 = *(const short8*)&ar[q * 8];
        short8 a1 = *(const short8*)&ar[32 + q * 8];
        short8 a2 = *(const short8*)&ar[64 + q * 8];
        short8 a3 = *(const short8*)&ar[96 + q * 8];
#pragma unroll
        for (int jt = 0; jt < 4; jt++) {
            int j = jt * 16 + nidx;
            const u16* wr = Wn1c + j * 128;
            floatx4 acc = {0.f, 0.f, 0.f, 0.f};
            acc = __builtin_amdgcn_mfma_f32_16x16x32_bf16(a0, *(const short8*)&wr[q * 8], acc, 0, 0, 0);
            acc = __builtin_amdgcn_mfma_f32_16x16x32_bf16(a1, *(const short8*)&wr[32 + q * 8], acc, 0, 0, 0);
            acc = __builtin_amdgcn_mfma_f32_16x16x32_bf16(a2, *(const short8*)&wr[64 + q * 8], acc, 0, 0, 0);
            acc = __builtin_amdgcn_mfma_f32_16x16x32_bf16(a3, *(const short8*)&wr[96 + q * 8], acc, 0, 0, 0);
#pragma unroll
            for (int r = 0; r < 4; r++) {
                int row = w * 16 + q * 4 + r;
                int n = n0 + row;
                if (n < NN) n1l1[n * 64 + j] = f2bf(fmaxf(acc[r], 0.f));
            }
        }
    }
}

// K5v5: lean fused edge pipeline, TPB tiles/block, TWO-DEEP prefetch pipeline:
// edata(t+2) in flight while gathers(t+1) issue from arrived edata(t+1) and tile t
// computes — no serial edata->gather chain inside one tile window. MFMA accumulator
// chains split 2+2 for ILP. Per-lane 4-edge run-merge -> direct global atomics.
__global__ __launch_bounds__(256) void k_edge5(
    const int2* __restrict__ edata, const u16* __restrict__ n1l0,
    const u16* __restrict__ Wfe0c, const void* __restrict__ bfe0,
    const float* __restrict__ PN, const u16* __restrict__ We1c,
    float* __restrict__ agg, const int* __restrict__ mf) {
    int m = mf[0];
    __shared__ __align__(16) u16 h1s[2][16][136];
    int t = threadIdx.x;
    int lane = t & 63, w = t >> 6, q = lane >> 4, nidx = lane & 15;
    // ---- per-block register hoists ----
    short8 wA[2][2];           // GEMM1 A-frags (swapped): W row = jt*16+nidx
    float bias[2][4], Pv[2][4], Nv[2][4];
#pragma unroll
    for (int jj = 0; jj < 2; jj++) {
        int jt = 2 * w + jj;
        const u16* wr = Wfe0c + (jt * 16 + nidx) * 128;
        wA[jj][0] = *(const short8*)&wr[q * 8];
        wA[jj][1] = *(const short8*)&wr[32 + q * 8];
#pragma unroll
        for (int r = 0; r < 4; r++) {
            int ch = jt * 16 + q * 4 + r;
            bias[jj][r] = ldf(bfe0, ch, m);
            Pv[jj][r] = PN[ch];
            Nv[jj][r] = PN[128 + ch];
        }
    }
    int c2 = w * 16 + nidx;
    const u16* wr2 = We1c + c2 * 128;
    short8 wB0 = *(const short8*)&wr2[q * 8];
    short8 wB1 = *(const short8*)&wr2[32 + q * 8];
    short8 wB2 = *(const short8*)&wr2[64 + q * 8];
    short8 wB3 = *(const short8*)&wr2[96 + q * 8];

    int e0 = blockIdx.x * (16 * TPB);
    // ---- pipeline prologue ----
    int2 edc = edata[e0 + nidx];                               // tile 0 meta
    int2 edn = edata[e0 + 16 + nidx];                          // tile 1 meta (TPB>=2)
    const u16* srow = n1l0 + ((size_t)(((unsigned)edc.x) & 0xFFFFu)) * 64;
    const u16* drow = n1l0 + ((size_t)(((unsigned)edc.x) >> 16)) * 64;
    short8 as0 = *(const short8*)&srow[q * 8];                 // gathers(0)
    short8 as1 = *(const short8*)&srow[32 + q * 8];
    short8 ad0 = *(const short8*)&drow[q * 8];
    short8 ad1 = *(const short8*)&drow[32 + q * 8];

    for (int tile = 0; tile < TPB; tile++) {
        // consume gathers(tile)
        short8 cs0 = as0, cs1 = as1, cd0 = ad0, cd1 = ad1;
        // issue gathers(tile+1) from edn (arrived: issued >=1 full tile ago)
        if (tile + 1 < TPB) {
            srow = n1l0 + ((size_t)(((unsigned)edn.x) & 0xFFFFu)) * 64;
            drow = n1l0 + ((size_t)(((unsigned)edn.x) >> 16)) * 64;
            as0 = *(const short8*)&srow[q * 8];
            as1 = *(const short8*)&srow[32 + q * 8];
            ad0 = *(const short8*)&drow[q * 8];
            ad1 = *(const short8*)&drow[32 + q * 8];
        }
        int2 edt = edc;                                        // tile meta for epilogue
        edc = edn;
        if (tile + 2 < TPB) edn = edata[e0 + (tile + 2) * 16 + nidx];   // 2-deep meta prefetch

        float aev = __int_as_float(edt.y);
        u16* hp = &h1s[tile & 1][0][0];
        // GEMM1 (swapped): channels jt*16+q*4+r for edge nidx; src/dst chains split for ILP
#pragma unroll
        for (int jj = 0; jj < 2; jj++) {
            floatx4 accS = {0.f, 0.f, 0.f, 0.f};
            floatx4 accD = {0.f, 0.f, 0.f, 0.f};
            accS = __builtin_amdgcn_mfma_f32_16x16x32_bf16(wA[jj][0], cs0, accS, 0, 0, 0);
            accD = __builtin_amdgcn_mfma_f32_16x16x32_bf16(wA[jj][0], cd0, accD, 0, 0, 0);
            accS = __builtin_amdgcn_mfma_f32_16x16x32_bf16(wA[jj][1], cs1, accS, 0, 0, 0);
            accD = __builtin_amdgcn_mfma_f32_16x16x32_bf16(wA[jj][1], cd1, accD, 0, 0, 0);
            float v0 = fmaxf(accS[0] + accD[0] + bias[jj][0] + aev * (aev > 0.f ? Pv[jj][0] : Nv[jj][0]), 0.f);
            float v1 = fmaxf(accS[1] + accD[1] + bias[jj][1] + aev * (aev > 0.f ? Pv[jj][1] : Nv[jj][1]), 0.f);
            float v2 = fmaxf(accS[2] + accD[2] + bias[jj][2] + aev * (aev > 0.f ? Pv[jj][2] : Nv[jj][2]), 0.f);
            float v3 = fmaxf(accS[3] + accD[3] + bias[jj][3] + aev * (aev > 0.f ? Pv[jj][3] : Nv[jj][3]), 0.f);
            unsigned lo = (unsigned)f2bf(v0) | ((unsigned)f2bf(v1) << 16);
            unsigned hi = (unsigned)f2bf(v2) | ((unsigned)f2bf(v3) << 16);
            uint2 pk; pk.x = lo; pk.y = hi;
            *(uint2*)&hp[nidx * 136 + w * 32 + jj * 16 + q * 4] = pk;
        }
        __syncthreads();
        // GEMM2: e1' = relu(h1 @ We1^T); D row=q*4+r=edge, col=nidx -> channel c2
        const u16* arow = &h1s[tile & 1][nidx][0];
        floatx4 accA = {0.f, 0.f, 0.f, 0.f};
        floatx4 accB = {0.f, 0.f, 0.f, 0.f};
        accA = __builtin_amdgcn_mfma_f32_16x16x32_bf16(*(const short8*)&arow[q * 8], wB0, accA, 0, 0, 0);
        accB = __builtin_amdgcn_mfma_f32_16x16x32_bf16(*(const short8*)&arow[32 + q * 8], wB1, accB, 0, 0, 0);
        accA = __builtin_amdgcn_mfma_f32_16x16x32_bf16(*(const short8*)&arow[64 + q * 8], wB2, accA, 0, 0, 0);
        accB = __builtin_amdgcn_mfma_f32_16x16x32_bf16(*(const short8*)&arow[96 + q * 8], wB3, accB, 0, 0, 0);
        // dsts of my 4 edges (q*4+r) via shfl of the tile's edge records
        unsigned x0 = (unsigned)__shfl(edt.x, q * 4 + 0);
        unsigned x1 = (unsigned)__shfl(edt.x, q * 4 + 1);
        unsigned x2 = (unsigned)__shfl(edt.x, q * 4 + 2);
        unsigned x3 = (unsigned)__shfl(edt.x, q * 4 + 3);
        unsigned d0 = x0 >> 16, d1 = x1 >> 16, d2 = x2 >> 16, d3 = x3 >> 16;
        float v0 = fmaxf(accA[0] + accB[0], 0.f);
        float v1 = fmaxf(accA[1] + accB[1], 0.f);
        float v2 = fmaxf(accA[2] + accB[2], 0.f);
        float v3 = fmaxf(accA[3] + accB[3], 0.f);
        float run = v0; unsigned cur = d0;
        if (d1 != cur) { atomicAdd(agg + cur * 64 + c2, run); run = v1; cur = d1; } else run += v1;
        if (d2 != cur) { atomicAdd(agg + cur * 64 + c2, run); run = v2; cur = d2; } else run += v2;
        if (d3 != cur) { atomicAdd(agg + cur * 64 + c2, run); run = v3; cur = d3; } else run += v3;
        atomicAdd(agg + cur * 64 + c2, run);
        // one barrier per tile: double-buffered h1s makes write(t+2) vs read(t) safe
    }
}

// K6: node MLP l1 + BN -> d_out. MFMA, 64 nodes/block.
__global__ __launch_bounds__(256) void k_node_l1(
    const u16* __restrict__ n1l1, const float* __restrict__ agg,
    const u16* __restrict__ Wfn1c, const void* __restrict__ bfn1,
    const void* __restrict__ g1, const void* __restrict__ b1,
    const void* __restrict__ rm1, const void* __restrict__ rv1,
    void* __restrict__ out, const int* __restrict__ mf) {
    int m = mf[0];
    __shared__ __align__(16) u16 fs[64][136];
    int t = threadIdx.x;
    int n0 = blockIdx.x * 64;
    {
        int col = t & 127;
        int rbase = t >> 7;
#pragma unroll
        for (int i = 0; i < 32; i++) {
            int row = rbase + 2 * i;
            int n = n0 + row;
            float v = 0.f;
            if (n < NN) v = (col < 64) ? agg[n * 64 + col] : bfu(n1l1[n * 64 + col - 64]);
            fs[row][col] = f2bf(v);
        }
    }
    __syncthreads();
    int lane = t & 63, w = t >> 6, q = lane >> 4, nidx = lane & 15;
    const u16* ar = &fs[w * 16 + nidx][0];
    short8 a0 = *(const short8*)&ar[q * 8];
    short8 a1 = *(const short8*)&ar[32 + q * 8];
    short8 a2 = *(const short8*)&ar[64 + q * 8];
    short8 a3 = *(const short8*)&ar[96 + q * 8];
#pragma unroll
    for (int jt = 0; jt < 8; jt++) {
        int j = jt * 16 + nidx;
        const u16* wr = Wfn1c + j * 128;
        floatx4 acc = {0.f, 0.f, 0.f, 0.f};
        acc = __builtin_amdgcn_mfma_f32_16x16x32_bf16(a0, *(const short8*)&wr[q * 8], acc, 0, 0, 0);
        acc = __builtin_amdgcn_mfma_f32_16x16x32_bf16(a1, *(const short8*)&wr[32 + q * 8], acc, 0, 0, 0);
        acc = __builtin_amdgcn_mfma_f32_16x16x32_bf16(a2, *(const short8*)&wr[64 + q * 8], acc, 0, 0, 0);
        acc = __builtin_amdgcn_mfma_f32_16x16x32_bf16(a3, *(const short8*)&wr[96 + q * 8], acc, 0, 0, 0);
        float bias = ldf(bfn1, j, m);
        float sc = ldf(g1, j, m) * rsqrtf(ldf(rv1, j, m) + BN_EPS);
        float sh = ldf(b1, j, m) - ldf(rm1, j, m) * sc;
#pragma unroll
        for (int r = 0; r < 4; r++) {
            int row = w * 16 + q * 4 + r;
            int n = n0 + row;
            if (n < NN) {
                float v = fmaxf(acc[r] + bias, 0.f) * sc + sh;
                if (m) ((float*)out)[n * 128 + j] = v;
                else   ((u16*)out)[n * 128 + j] = f2bf(v);
            }
        }
    }
}

extern "C" void kernel_launch(void* const* d_in, const int* in_sizes, int n_in,
                              void* d_out, int out_size, void* d_ws, size_t ws_size,
                              hipStream_t stream) {
    const void* x    = d_in[0];
    const void* ea   = d_in[1];
    const int*  ei   = (const int*)d_in[2];
    const void* Wn0  = d_in[3];
    const void* We0  = d_in[4];
    const void* Wfn0 = d_in[5];
    const void* bfn0 = d_in[6];
    const void* Wfe0 = d_in[7];
    const void* bfe0 = d_in[8];
    const void* g0   = d_in[9];
    const void* b0   = d_in[10];
    const void* rm0  = d_in[11];
    const void* rv0  = d_in[12];
    const void* Wn1  = d_in[13];
    const void* We1  = d_in[14];
    const void* Wfn1 = d_in[15];
    const void* bfn1 = d_in[16];
    // d_in[17]/d_in[18] (l1_Wfe/l1_bfe): dead — layer-1 edge output discarded
    const void* g1   = d_in[19];
    const void* b1   = d_in[20];
    const void* rm1  = d_in[21];
    const void* rv1  = d_in[22];

    float* wsf    = (float*)d_ws;
    float* agg    = wsf;                          // 3,200,000 f32
    u16*   n1l0   = (u16*)(wsf + 3200000);        // 3.2M u16
    u16*   n1l1   = (u16*)(wsf + 4800000);        // 3.2M u16
    float* sp     = wsf + 6400000;                // 50,000
    float* sn     = wsf + 6450000;                // 50,000
    int*   cnt    = (int*)(wsf + 6500000);        // 50,000
    int*   cursor = (int*)(wsf + 6550000);        // 50,000
    int*   bsum   = (int*)(wsf + 6600000);        // 256
    float* PN     = wsf + 6600256;                // 256
    u16*   Wc     = (u16*)(wsf + 6600512);        // 65,536 u16 canonical weights
    int*   mode   = (int*)(wsf + 6633280);        // 1
    int2*  edata  = (int2*)(wsf + 6633284);       // 1,600,000 x 8B (dst-sorted edge records)
    u16* Wfe0c = Wc;
    u16* We1c  = Wc + 16384;
    u16* Wfn0c = Wc + 24576;
    u16* Wn1c  = Wc + 40960;
    u16* Wfn1c = Wc + 49152;

    // Zero sp + sn + cnt (contiguous) and agg (atomic-accumulated).
    hipMemsetAsync(sp, 0, 150000 * sizeof(float), stream);
    hipMemsetAsync(agg, 0, 3200000 * sizeof(float), stream);

    k_cvtw<<<256, 256, 0, stream>>>((const u16*)x, Wfe0, We1, Wfn0, Wn1, Wfn1, Wc, mode);
    k_enc0h<<<9375, 256, 0, stream>>>(x, Wn0, n1l0, ei, cnt, mode);
    k_scan1<<<NSCAN, 256, 0, stream>>>(cnt, bsum);
    k_scan2pn<<<1, 256, 0, stream>>>(bsum, We0, Wfe0, PN, mode);
    k_scan3<<<NSCAN, 256, 0, stream>>>(cnt, bsum, cursor);
    k_scatter<<<6250, 256, 0, stream>>>(ea, ei, cursor, edata, sp, sn, mode);
    k_node_l0<<<782, 256, 0, stream>>>(n1l0, sp, sn, We0, Wfn0c, bfn0,
                                       g0, b0, rm0, rv0, Wn1c, n1l1, mode);
    k_edge5<<<NE / (16 * TPB), 256, 0, stream>>>(edata, n1l0, Wfe0c, bfe0, PN, We1c, agg, mode);
    k_node_l1<<<782, 256, 0, stream>>>(n1l1, agg, Wfn1c, bfn1,
                                       g1, b1, rm1, rv1, d_out, mode);
}

// Round 6
// 615.819 us; speedup vs baseline: 1.2706x; 1.2706x over previous
//
#include <hip/hip_runtime.h>

typedef unsigned short u16;
typedef __attribute__((ext_vector_type(8))) short short8;
typedef __attribute__((ext_vector_type(4))) float floatx4;

#define NN 50000
#define NE 1600000
#define BN_EPS 1e-5f
#define TPB 8                 // 16-edge tiles per k_edge6 block

__device__ __forceinline__ float bfu(u16 u) {
    union { unsigned u32; float f; } v; v.u32 = ((unsigned)u) << 16; return v.f;
}
__device__ __forceinline__ u16 f2bf(float f) {
    union { float f; unsigned u; } v; v.f = f;
    unsigned r = v.u + 0x7FFFu + ((v.u >> 16) & 1u);
    return (u16)(r >> 16);
}
// mode m: 1 = buffers hold float32, 0 = buffers hold bf16
__device__ __forceinline__ float ldf(const void* p, int i, int m) {
    return m ? ((const float*)p)[i] : bfu(((const u16*)p)[i]);
}

// K0b: canonicalize all MFMA-consumed weights to bf16 ws copies, with INLINE dtype
// detection (every block recomputes mode from x; block 0 publishes it). Block 256
// computes the PN rank-1 vectors instead of converting weights.
// Layout in dst: Wfe0[16384] | We1[8192] | Wfn0[16384] | Wn1[8192] | Wfn1[16384]
__global__ __launch_bounds__(256) void k_cvtw(const u16* __restrict__ x,
                                              const void* __restrict__ W0, const void* __restrict__ W1,
                                              const void* __restrict__ W2, const void* __restrict__ W3,
                                              const void* __restrict__ W4,
                                              const void* __restrict__ We0raw,
                                              u16* __restrict__ dst, float* __restrict__ PN,
                                              int* __restrict__ mode) {
    int t = threadIdx.x;
    __shared__ float sred[4];
    float mx = 0.f;
    for (int i = t; i < 4096; i += 256) mx = fmaxf(mx, fabsf(bfu(x[i])));
#pragma unroll
    for (int o = 32; o > 0; o >>= 1) mx = fmaxf(mx, __shfl_down(mx, o));
    if ((t & 63) == 0) sred[t >> 6] = mx;
    __syncthreads();
    float m2 = fmaxf(fmaxf(sred[0], sred[1]), fmaxf(sred[2], sred[3]));
    int m = (m2 > 1e4f) ? 1 : 0;
    if (blockIdx.x == 0 && t == 0) mode[0] = m;
    if (blockIdx.x == 256) {   // PN block: P[j]/N[j] from raw We0 + raw Wfe0 (W0)
        if (t < 128) {
            float p = 0.f, n = 0.f;
            for (int k = 0; k < 64; k++) {
                float w = ldf(We0raw, k, m);
                float wf = ldf(W0, t * 128 + 64 + k, m);
                p += fmaxf(w, 0.f) * wf;
                n += fminf(w, 0.f) * wf;
            }
            PN[t] = p; PN[128 + t] = n;
        }
        return;
    }
    int i = blockIdx.x * 256 + t;   // 65536 total
    const void* src; int off;
    if (i < 16384)      { src = W0; off = i; }
    else if (i < 24576) { src = W1; off = i - 16384; }
    else if (i < 40960) { src = W2; off = i - 24576; }
    else if (i < 49152) { src = W3; off = i - 40960; }
    else                { src = W4; off = i - 49152; }
    dst[i] = m ? f2bf(((const float*)src)[off]) : ((const u16*)src)[off];
}

// K1h: fused {node encoder l0 (16 nodes/block)} + {per-node +/- edge_attr sums} via block split.
__global__ __launch_bounds__(256) void k_enc0h(const void* __restrict__ x, const void* __restrict__ Wn,
                                               u16* __restrict__ n1, const int* __restrict__ ei,
                                               const void* __restrict__ ea,
                                               float* __restrict__ sp, float* __restrict__ sn,
                                               const int* __restrict__ mf) {
    int b = blockIdx.x;
    int t = threadIdx.x;
    int m = mf[0];
    if (b >= 3125) {   // esum part: 6250 blocks
        int e = (b - 3125) * 256 + t;
        float a = ldf(ea, e, m);
        int d = ei[NE + e];
        if (a > 0.f) atomicAdd(sp + d, a);
        else if (a < 0.f) atomicAdd(sn + d, a);
        return;
    }
    __shared__ float Wns[64 * 17];
    __shared__ float xsh[16][17];
    int n0 = b * 16;
    for (int i = t; i < 1024; i += 256) Wns[(i >> 4) * 17 + (i & 15)] = ldf(Wn, i, m);
    xsh[t >> 4][t & 15] = ldf(x, n0 * 16 + t, m);
    __syncthreads();
    int c = t & 63, ng = t >> 6;   // ng: node group 0..3, nodes ng*4..ng*4+3
    float a0 = 0.f, a1 = 0.f, a2 = 0.f, a3 = 0.f;
#pragma unroll
    for (int k = 0; k < 16; k++) {
        float wv = Wns[c * 17 + k];
        a0 += xsh[ng * 4 + 0][k] * wv;
        a1 += xsh[ng * 4 + 1][k] * wv;
        a2 += xsh[ng * 4 + 2][k] * wv;
        a3 += xsh[ng * 4 + 3][k] * wv;
    }
    n1[(n0 + ng * 4 + 0) * 64 + c] = f2bf(fmaxf(a0, 0.f));
    n1[(n0 + ng * 4 + 1) * 64 + c] = f2bf(fmaxf(a1, 0.f));
    n1[(n0 + ng * 4 + 2) * 64 + c] = f2bf(fmaxf(a2, 0.f));
    n1[(n0 + ng * 4 + 3) * 64 + c] = f2bf(fmaxf(a3, 0.f));
}

// K34: fused node MLP l0 + BN + node encoder l1 -> n1_l1 [50000 x 64] bf16. MFMA, 64 nodes/block.
__global__ __launch_bounds__(256) void k_node_l0(
    const u16* __restrict__ n1l0, const float* __restrict__ sp, const float* __restrict__ sn,
    const void* __restrict__ We0, const u16* __restrict__ Wfn0c, const void* __restrict__ bfn0,
    const void* __restrict__ g0, const void* __restrict__ b0,
    const void* __restrict__ rm0, const void* __restrict__ rv0,
    const u16* __restrict__ Wn1c, u16* __restrict__ n1l1, const int* __restrict__ mf) {
    int m = mf[0];
    __shared__ __align__(16) u16 fs[64][136];
    __shared__ __align__(16) u16 xs[64][136];
    int t = threadIdx.x;
    int n0 = blockIdx.x * 64;
    {   // fs[row][col] = concat(analytic agg_l0, n1_l0), bf16
        int col = t & 127;
        int rbase = t >> 7;              // 0 or 1
        float wp = 0.f, wn = 0.f;
        if (col < 64) { float w0 = ldf(We0, col, m); wp = fmaxf(w0, 0.f); wn = fminf(w0, 0.f); }
#pragma unroll
        for (int i = 0; i < 32; i++) {
            int row = rbase + 2 * i;
            int n = n0 + row;
            float v = 0.f;
            if (n < NN) v = (col < 64) ? (wp * sp[n] + wn * sn[n]) : bfu(n1l0[n * 64 + col - 64]);
            fs[row][col] = f2bf(v);
        }
    }
    __syncthreads();
    int lane = t & 63, w = t >> 6, q = lane >> 4, nidx = lane & 15;
    {
        const u16* ar = &fs[w * 16 + nidx][0];
        short8 a0 = *(const short8*)&ar[q * 8];
        short8 a1 = *(const short8*)&ar[32 + q * 8];
        short8 a2 = *(const short8*)&ar[64 + q * 8];
        short8 a3 = *(const short8*)&ar[96 + q * 8];
#pragma unroll
        for (int jt = 0; jt < 8; jt++) {
            int j = jt * 16 + nidx;
            const u16* wr = Wfn0c + j * 128;
            floatx4 acc = {0.f, 0.f, 0.f, 0.f};
            acc = __builtin_amdgcn_mfma_f32_16x16x32_bf16(a0, *(const short8*)&wr[q * 8], acc, 0, 0, 0);
            acc = __builtin_amdgcn_mfma_f32_16x16x32_bf16(a1, *(const short8*)&wr[32 + q * 8], acc, 0, 0, 0);
            acc = __builtin_amdgcn_mfma_f32_16x16x32_bf16(a2, *(const short8*)&wr[64 + q * 8], acc, 0, 0, 0);
            acc = __builtin_amdgcn_mfma_f32_16x16x32_bf16(a3, *(const short8*)&wr[96 + q * 8], acc, 0, 0, 0);
            float bias = ldf(bfn0, j, m);
            float sc = ldf(g0, j, m) * rsqrtf(ldf(rv0, j, m) + BN_EPS);
            float sh = ldf(b0, j, m) - ldf(rm0, j, m) * sc;
#pragma unroll
            for (int r = 0; r < 4; r++) {
                int row = w * 16 + q * 4 + r;
                xs[row][j] = f2bf(fmaxf(acc[r] + bias, 0.f) * sc + sh);
            }
        }
    }
    __syncthreads();
    {
        const u16* ar = &xs[w * 16 + nidx][0];
        short8 a0 = *(const short8*)&ar[q * 8];
        short8 a1 = *(const short8*)&ar[32 + q * 8];
        short8 a2 = *(const short8*)&ar[64 + q * 8];
        short8 a3 = *(const short8*)&ar[96 + q * 8];
#pragma unroll
        for (int jt = 0; jt < 4; jt++) {
            int j = jt * 16 + nidx;
            const u16* wr = Wn1c + j * 128;
            floatx4 acc = {0.f, 0.f, 0.f, 0.f};
            acc = __builtin_amdgcn_mfma_f32_16x16x32_bf16(a0, *(const short8*)&wr[q * 8], acc, 0, 0, 0);
            acc = __builtin_amdgcn_mfma_f32_16x16x32_bf16(a1, *(const short8*)&wr[32 + q * 8], acc, 0, 0, 0);
            acc = __builtin_amdgcn_mfma_f32_16x16x32_bf16(a2, *(const short8*)&wr[64 + q * 8], acc, 0, 0, 0);
            acc = __builtin_amdgcn_mfma_f32_16x16x32_bf16(a3, *(const short8*)&wr[96 + q * 8], acc, 0, 0, 0);
#pragma unroll
            for (int r = 0; r < 4; r++) {
                int row = w * 16 + q * 4 + r;
                int n = n0 + row;
                if (n < NN) n1l1[n * 64 + j] = f2bf(fmaxf(acc[r], 0.f));
            }
        }
    }
}

// K5v6: lean fused edge pipeline on UNSORTED edges (sort pipeline removed — its only
// benefit, atomic reduction, was proven worthless in r0 vs r2). r4 structure: TPB
// 16-edge tiles/block, weights/bias/PN register-hoisted once, distributive gather-free
// GEMM1 (operand-swapped), double-buffered h1s, 1 barrier/tile, 1-deep prefetch.
__global__ __launch_bounds__(256) void k_edge6(
    const int* __restrict__ ei, const void* __restrict__ ea, const u16* __restrict__ n1l0,
    const u16* __restrict__ Wfe0c, const void* __restrict__ bfe0,
    const float* __restrict__ PN, const u16* __restrict__ We1c,
    float* __restrict__ agg, const int* __restrict__ mf) {
    int m = mf[0];
    __shared__ __align__(16) u16 h1s[2][16][136];
    int t = threadIdx.x;
    int lane = t & 63, w = t >> 6, q = lane >> 4, nidx = lane & 15;
    // ---- per-block register hoists ----
    short8 wA[2][2];           // GEMM1 A-frags (swapped): W row = jt*16+nidx
    float bias[2][4], Pv[2][4], Nv[2][4];
#pragma unroll
    for (int jj = 0; jj < 2; jj++) {
        int jt = 2 * w + jj;
        const u16* wr = Wfe0c + (jt * 16 + nidx) * 128;
        wA[jj][0] = *(const short8*)&wr[q * 8];
        wA[jj][1] = *(const short8*)&wr[32 + q * 8];
#pragma unroll
        for (int r = 0; r < 4; r++) {
            int ch = jt * 16 + q * 4 + r;
            bias[jj][r] = ldf(bfe0, ch, m);
            Pv[jj][r] = PN[ch];
            Nv[jj][r] = PN[128 + ch];
        }
    }
    int c2 = w * 16 + nidx;
    const u16* wr2 = We1c + c2 * 128;
    short8 wB0 = *(const short8*)&wr2[q * 8];
    short8 wB1 = *(const short8*)&wr2[32 + q * 8];
    short8 wB2 = *(const short8*)&wr2[64 + q * 8];
    short8 wB3 = *(const short8*)&wr2[96 + q * 8];

    int e0 = blockIdx.x * (16 * TPB);
    // ---- prologue: tile 0 loads ----
    int eb = e0 + nidx;
    int sv = ei[eb];
    int dv = ei[NE + eb];
    float av = ldf(ea, eb, m);
    const u16* srow = n1l0 + (size_t)sv * 64;
    const u16* drow = n1l0 + (size_t)dv * 64;
    short8 as0 = *(const short8*)&srow[q * 8];
    short8 as1 = *(const short8*)&srow[32 + q * 8];
    short8 ad0 = *(const short8*)&drow[q * 8];
    short8 ad1 = *(const short8*)&drow[32 + q * 8];

    for (int tile = 0; tile < TPB; tile++) {
        short8 cs0 = as0, cs1 = as1, cd0 = ad0, cd1 = ad1;
        int curd = dv;
        float cura = av;
        if (tile + 1 < TPB) {   // issue next tile's loads early (hidden under GEMMs)
            int en = e0 + (tile + 1) * 16 + nidx;
            sv = ei[en];
            dv = ei[NE + en];
            av = ldf(ea, en, m);
            srow = n1l0 + (size_t)sv * 64;
            drow = n1l0 + (size_t)dv * 64;
            as0 = *(const short8*)&srow[q * 8];
            as1 = *(const short8*)&srow[32 + q * 8];
            ad0 = *(const short8*)&drow[q * 8];
            ad1 = *(const short8*)&drow[32 + q * 8];
        }
        u16* hp = &h1s[tile & 1][0][0];
        // GEMM1 (swapped): channels jt*16+q*4+r for edge nidx; src/dst chains split for ILP
#pragma unroll
        for (int jj = 0; jj < 2; jj++) {
            floatx4 accS = {0.f, 0.f, 0.f, 0.f};
            floatx4 accD = {0.f, 0.f, 0.f, 0.f};
            accS = __builtin_amdgcn_mfma_f32_16x16x32_bf16(wA[jj][0], cs0, accS, 0, 0, 0);
            accD = __builtin_amdgcn_mfma_f32_16x16x32_bf16(wA[jj][0], cd0, accD, 0, 0, 0);
            accS = __builtin_amdgcn_mfma_f32_16x16x32_bf16(wA[jj][1], cs1, accS, 0, 0, 0);
            accD = __builtin_amdgcn_mfma_f32_16x16x32_bf16(wA[jj][1], cd1, accD, 0, 0, 0);
            float v0 = fmaxf(accS[0] + accD[0] + bias[jj][0] + cura * (cura > 0.f ? Pv[jj][0] : Nv[jj][0]), 0.f);
            float v1 = fmaxf(accS[1] + accD[1] + bias[jj][1] + cura * (cura > 0.f ? Pv[jj][1] : Nv[jj][1]), 0.f);
            float v2 = fmaxf(accS[2] + accD[2] + bias[jj][2] + cura * (cura > 0.f ? Pv[jj][2] : Nv[jj][2]), 0.f);
            float v3 = fmaxf(accS[3] + accD[3] + bias[jj][3] + cura * (cura > 0.f ? Pv[jj][3] : Nv[jj][3]), 0.f);
            unsigned lo = (unsigned)f2bf(v0) | ((unsigned)f2bf(v1) << 16);
            unsigned hi = (unsigned)f2bf(v2) | ((unsigned)f2bf(v3) << 16);
            uint2 pk; pk.x = lo; pk.y = hi;
            *(uint2*)&hp[nidx * 136 + w * 32 + jj * 16 + q * 4] = pk;
        }
        __syncthreads();
        // GEMM2: e1' = relu(h1 @ We1^T); D row=q*4+r=edge, col=nidx -> channel c2
        const u16* arow = &h1s[tile & 1][nidx][0];
        floatx4 accA = {0.f, 0.f, 0.f, 0.f};
        floatx4 accB = {0.f, 0.f, 0.f, 0.f};
        accA = __builtin_amdgcn_mfma_f32_16x16x32_bf16(*(const short8*)&arow[q * 8], wB0, accA, 0, 0, 0);
        accB = __builtin_amdgcn_mfma_f32_16x16x32_bf16(*(const short8*)&arow[32 + q * 8], wB1, accB, 0, 0, 0);
        accA = __builtin_amdgcn_mfma_f32_16x16x32_bf16(*(const short8*)&arow[64 + q * 8], wB2, accA, 0, 0, 0);
        accB = __builtin_amdgcn_mfma_f32_16x16x32_bf16(*(const short8*)&arow[96 + q * 8], wB3, accB, 0, 0, 0);
        // dsts of my 4 edges (q*4+r) via shfl of the tile's per-lane dst
        int d0 = __shfl(curd, q * 4 + 0);
        int d1 = __shfl(curd, q * 4 + 1);
        int d2 = __shfl(curd, q * 4 + 2);
        int d3 = __shfl(curd, q * 4 + 3);
        atomicAdd(agg + (size_t)d0 * 64 + c2, fmaxf(accA[0] + accB[0], 0.f));
        atomicAdd(agg + (size_t)d1 * 64 + c2, fmaxf(accA[1] + accB[1], 0.f));
        atomicAdd(agg + (size_t)d2 * 64 + c2, fmaxf(accA[2] + accB[2], 0.f));
        atomicAdd(agg + (size_t)d3 * 64 + c2, fmaxf(accA[3] + accB[3], 0.f));
        // one barrier per tile: double-buffered h1s makes write(t+2) vs read(t) safe
    }
}

// K6: node MLP l1 + BN -> d_out. MFMA, 64 nodes/block.
__global__ __launch_bounds__(256) void k_node_l1(
    const u16* __restrict__ n1l1, const float* __restrict__ agg,
    const u16* __restrict__ Wfn1c, const void* __restrict__ bfn1,
    const void* __restrict__ g1, const void* __restrict__ b1,
    const void* __restrict__ rm1, const void* __restrict__ rv1,
    void* __restrict__ out, const int* __restrict__ mf) {
    int m = mf[0];
    __shared__ __align__(16) u16 fs[64][136];
    int t = threadIdx.x;
    int n0 = blockIdx.x * 64;
    {
        int col = t & 127;
        int rbase = t >> 7;
#pragma unroll
        for (int i = 0; i < 32; i++) {
            int row = rbase + 2 * i;
            int n = n0 + row;
            float v = 0.f;
            if (n < NN) v = (col < 64) ? agg[n * 64 + col] : bfu(n1l1[n * 64 + col - 64]);
            fs[row][col] = f2bf(v);
        }
    }
    __syncthreads();
    int lane = t & 63, w = t >> 6, q = lane >> 4, nidx = lane & 15;
    const u16* ar = &fs[w * 16 + nidx][0];
    short8 a0 = *(const short8*)&ar[q * 8];
    short8 a1 = *(const short8*)&ar[32 + q * 8];
    short8 a2 = *(const short8*)&ar[64 + q * 8];
    short8 a3 = *(const short8*)&ar[96 + q * 8];
#pragma unroll
    for (int jt = 0; jt < 8; jt++) {
        int j = jt * 16 + nidx;
        const u16* wr = Wfn1c + j * 128;
        floatx4 acc = {0.f, 0.f, 0.f, 0.f};
        acc = __builtin_amdgcn_mfma_f32_16x16x32_bf16(a0, *(const short8*)&wr[q * 8], acc, 0, 0, 0);
        acc = __builtin_amdgcn_mfma_f32_16x16x32_bf16(a1, *(const short8*)&wr[32 + q * 8], acc, 0, 0, 0);
        acc = __builtin_amdgcn_mfma_f32_16x16x32_bf16(a2, *(const short8*)&wr[64 + q * 8], acc, 0, 0, 0);
        acc = __builtin_amdgcn_mfma_f32_16x16x32_bf16(a3, *(const short8*)&wr[96 + q * 8], acc, 0, 0, 0);
        float bias = ldf(bfn1, j, m);
        float sc = ldf(g1, j, m) * rsqrtf(ldf(rv1, j, m) + BN_EPS);
        float sh = ldf(b1, j, m) - ldf(rm1, j, m) * sc;
#pragma unroll
        for (int r = 0; r < 4; r++) {
            int row = w * 16 + q * 4 + r;
            int n = n0 + row;
            if (n < NN) {
                float v = fmaxf(acc[r] + bias, 0.f) * sc + sh;
                if (m) ((float*)out)[n * 128 + j] = v;
                else   ((u16*)out)[n * 128 + j] = f2bf(v);
            }
        }
    }
}

extern "C" void kernel_launch(void* const* d_in, const int* in_sizes, int n_in,
                              void* d_out, int out_size, void* d_ws, size_t ws_size,
                              hipStream_t stream) {
    const void* x    = d_in[0];
    const void* ea   = d_in[1];
    const int*  ei   = (const int*)d_in[2];
    const void* Wn0  = d_in[3];
    const void* We0  = d_in[4];
    const void* Wfn0 = d_in[5];
    const void* bfn0 = d_in[6];
    const void* Wfe0 = d_in[7];
    const void* bfe0 = d_in[8];
    const void* g0   = d_in[9];
    const void* b0   = d_in[10];
    const void* rm0  = d_in[11];
    const void* rv0  = d_in[12];
    const void* Wn1  = d_in[13];
    const void* We1  = d_in[14];
    const void* Wfn1 = d_in[15];
    const void* bfn1 = d_in[16];
    // d_in[17]/d_in[18] (l1_Wfe/l1_bfe): dead — layer-1 edge output discarded
    const void* g1   = d_in[19];
    const void* b1   = d_in[20];
    const void* rm1  = d_in[21];
    const void* rv1  = d_in[22];

    float* wsf    = (float*)d_ws;
    float* agg    = wsf;                          // 3,200,000 f32
    u16*   n1l0   = (u16*)(wsf + 3200000);        // 3.2M u16
    u16*   n1l1   = (u16*)(wsf + 4800000);        // 3.2M u16
    float* sp     = wsf + 6400000;                // 50,000
    float* sn     = wsf + 6450000;                // 50,000
    float* PN     = wsf + 6500000;                // 256
    u16*   Wc     = (u16*)(wsf + 6500256);        // 65,536 u16 canonical weights
    int*   mode   = (int*)(wsf + 6533024);        // 1
    u16* Wfe0c = Wc;
    u16* We1c  = Wc + 16384;
    u16* Wfn0c = Wc + 24576;
    u16* Wn1c  = Wc + 40960;
    u16* Wfn1c = Wc + 49152;

    // Zero sp + sn (contiguous) and agg (atomic-accumulated).
    hipMemsetAsync(sp, 0, 100000 * sizeof(float), stream);
    hipMemsetAsync(agg, 0, 3200000 * sizeof(float), stream);

    k_cvtw<<<257, 256, 0, stream>>>((const u16*)x, Wfe0, We1, Wfn0, Wn1, Wfn1,
                                    We0, Wc, PN, mode);
    k_enc0h<<<9375, 256, 0, stream>>>(x, Wn0, n1l0, ei, ea, sp, sn, mode);
    k_node_l0<<<782, 256, 0, stream>>>(n1l0, sp, sn, We0, Wfn0c, bfn0,
                                       g0, b0, rm0, rv0, Wn1c, n1l1, mode);
    k_edge6<<<NE / (16 * TPB), 256, 0, stream>>>(ei, ea, n1l0, Wfe0c, bfe0, PN, We1c, agg, mode);
    k_node_l1<<<782, 256, 0, stream>>>(n1l1, agg, Wfn1c, bfn1,
                                       g1, b1, rm1, rv1, d_out, mode);
}

// Round 7
// 614.420 us; speedup vs baseline: 1.2735x; 1.0023x over previous
//
#include <hip/hip_runtime.h>

typedef unsigned short u16;
typedef __attribute__((ext_vector_type(8))) short short8;
typedef __attribute__((ext_vector_type(4))) float floatx4;

#define NN 50000
#define NE 1600000
#define BN_EPS 1e-5f
#define TPB 8                 // 16-edge tiles per k_edge7 block

// LDS-only barrier: drains lgkmcnt (DS ops) but NOT vmcnt — in-flight global
// atomics/loads survive across it. __syncthreads() would emit
// "s_waitcnt vmcnt(0) lgkmcnt(0); s_barrier", putting every tile's 4 random-address
// global atomics (400-900 cy L2/HBM round trip) on the barrier critical path.
#define LDS_BARRIER() asm volatile("s_waitcnt lgkmcnt(0)\n\ts_barrier" ::: "memory")

__device__ __forceinline__ float bfu(u16 u) {
    union { unsigned u32; float f; } v; v.u32 = ((unsigned)u) << 16; return v.f;
}
__device__ __forceinline__ u16 f2bf(float f) {
    union { float f; unsigned u; } v; v.f = f;
    unsigned r = v.u + 0x7FFFu + ((v.u >> 16) & 1u);
    return (u16)(r >> 16);
}
// mode m: 1 = buffers hold float32, 0 = buffers hold bf16
__device__ __forceinline__ float ldf(const void* p, int i, int m) {
    return m ? ((const float*)p)[i] : bfu(((const u16*)p)[i]);
}

// K0b: canonicalize all MFMA-consumed weights to bf16 ws copies, with INLINE dtype
// detection (every block recomputes mode from x; block 0 publishes it). Block 256
// computes the PN rank-1 vectors instead of converting weights.
// Layout in dst: Wfe0[16384] | We1[8192] | Wfn0[16384] | Wn1[8192] | Wfn1[16384]
__global__ __launch_bounds__(256) void k_cvtw(const u16* __restrict__ x,
                                              const void* __restrict__ W0, const void* __restrict__ W1,
                                              const void* __restrict__ W2, const void* __restrict__ W3,
                                              const void* __restrict__ W4,
                                              const void* __restrict__ We0raw,
                                              u16* __restrict__ dst, float* __restrict__ PN,
                                              int* __restrict__ mode) {
    int t = threadIdx.x;
    __shared__ float sred[4];
    float mx = 0.f;
    for (int i = t; i < 4096; i += 256) mx = fmaxf(mx, fabsf(bfu(x[i])));
#pragma unroll
    for (int o = 32; o > 0; o >>= 1) mx = fmaxf(mx, __shfl_down(mx, o));
    if ((t & 63) == 0) sred[t >> 6] = mx;
    __syncthreads();
    float m2 = fmaxf(fmaxf(sred[0], sred[1]), fmaxf(sred[2], sred[3]));
    int m = (m2 > 1e4f) ? 1 : 0;
    if (blockIdx.x == 0 && t == 0) mode[0] = m;
    if (blockIdx.x == 256) {   // PN block: P[j]/N[j] from raw We0 + raw Wfe0 (W0)
        if (t < 128) {
            float p = 0.f, n = 0.f;
            for (int k = 0; k < 64; k++) {
                float w = ldf(We0raw, k, m);
                float wf = ldf(W0, t * 128 + 64 + k, m);
                p += fmaxf(w, 0.f) * wf;
                n += fminf(w, 0.f) * wf;
            }
            PN[t] = p; PN[128 + t] = n;
        }
        return;
    }
    int i = blockIdx.x * 256 + t;   // 65536 total
    const void* src; int off;
    if (i < 16384)      { src = W0; off = i; }
    else if (i < 24576) { src = W1; off = i - 16384; }
    else if (i < 40960) { src = W2; off = i - 24576; }
    else if (i < 49152) { src = W3; off = i - 40960; }
    else                { src = W4; off = i - 49152; }
    dst[i] = m ? f2bf(((const float*)src)[off]) : ((const u16*)src)[off];
}

// K1h: fused {node encoder l0 (16 nodes/block)} + {per-node +/- edge_attr sums} via block split.
__global__ __launch_bounds__(256) void k_enc0h(const void* __restrict__ x, const void* __restrict__ Wn,
                                               u16* __restrict__ n1, const int* __restrict__ ei,
                                               const void* __restrict__ ea,
                                               float* __restrict__ sp, float* __restrict__ sn,
                                               const int* __restrict__ mf) {
    int b = blockIdx.x;
    int t = threadIdx.x;
    int m = mf[0];
    if (b >= 3125) {   // esum part: 6250 blocks
        int e = (b - 3125) * 256 + t;
        float a = ldf(ea, e, m);
        int d = ei[NE + e];
        if (a > 0.f) atomicAdd(sp + d, a);
        else if (a < 0.f) atomicAdd(sn + d, a);
        return;
    }
    __shared__ float Wns[64 * 17];
    __shared__ float xsh[16][17];
    int n0 = b * 16;
    for (int i = t; i < 1024; i += 256) Wns[(i >> 4) * 17 + (i & 15)] = ldf(Wn, i, m);
    xsh[t >> 4][t & 15] = ldf(x, n0 * 16 + t, m);
    __syncthreads();
    int c = t & 63, ng = t >> 6;   // ng: node group 0..3, nodes ng*4..ng*4+3
    float a0 = 0.f, a1 = 0.f, a2 = 0.f, a3 = 0.f;
#pragma unroll
    for (int k = 0; k < 16; k++) {
        float wv = Wns[c * 17 + k];
        a0 += xsh[ng * 4 + 0][k] * wv;
        a1 += xsh[ng * 4 + 1][k] * wv;
        a2 += xsh[ng * 4 + 2][k] * wv;
        a3 += xsh[ng * 4 + 3][k] * wv;
    }
    n1[(n0 + ng * 4 + 0) * 64 + c] = f2bf(fmaxf(a0, 0.f));
    n1[(n0 + ng * 4 + 1) * 64 + c] = f2bf(fmaxf(a1, 0.f));
    n1[(n0 + ng * 4 + 2) * 64 + c] = f2bf(fmaxf(a2, 0.f));
    n1[(n0 + ng * 4 + 3) * 64 + c] = f2bf(fmaxf(a3, 0.f));
}

// K34: fused node MLP l0 + BN + node encoder l1 -> n1_l1 [50000 x 64] bf16. MFMA, 64 nodes/block.
__global__ __launch_bounds__(256) void k_node_l0(
    const u16* __restrict__ n1l0, const float* __restrict__ sp, const float* __restrict__ sn,
    const void* __restrict__ We0, const u16* __restrict__ Wfn0c, const void* __restrict__ bfn0,
    const void* __restrict__ g0, const void* __restrict__ b0,
    const void* __restrict__ rm0, const void* __restrict__ rv0,
    const u16* __restrict__ Wn1c, u16* __restrict__ n1l1, const int* __restrict__ mf) {
    int m = mf[0];
    __shared__ __align__(16) u16 fs[64][136];
    __shared__ __align__(16) u16 xs[64][136];
    int t = threadIdx.x;
    int n0 = blockIdx.x * 64;
    {   // fs[row][col] = concat(analytic agg_l0, n1_l0), bf16
        int col = t & 127;
        int rbase = t >> 7;              // 0 or 1
        float wp = 0.f, wn = 0.f;
        if (col < 64) { float w0 = ldf(We0, col, m); wp = fmaxf(w0, 0.f); wn = fminf(w0, 0.f); }
#pragma unroll
        for (int i = 0; i < 32; i++) {
            int row = rbase + 2 * i;
            int n = n0 + row;
            float v = 0.f;
            if (n < NN) v = (col < 64) ? (wp * sp[n] + wn * sn[n]) : bfu(n1l0[n * 64 + col - 64]);
            fs[row][col] = f2bf(v);
        }
    }
    __syncthreads();
    int lane = t & 63, w = t >> 6, q = lane >> 4, nidx = lane & 15;
    {
        const u16* ar = &fs[w * 16 + nidx][0];
        short8 a0 = *(const short8*)&ar[q * 8];
        short8 a1 = *(const short8*)&ar[32 + q * 8];
        short8 a2 = *(const short8*)&ar[64 + q * 8];
        short8 a3 = *(const short8*)&ar[96 + q * 8];
#pragma unroll
        for (int jt = 0; jt < 8; jt++) {
            int j = jt * 16 + nidx;
            const u16* wr = Wfn0c + j * 128;
            floatx4 acc = {0.f, 0.f, 0.f, 0.f};
            acc = __builtin_amdgcn_mfma_f32_16x16x32_bf16(a0, *(const short8*)&wr[q * 8], acc, 0, 0, 0);
            acc = __builtin_amdgcn_mfma_f32_16x16x32_bf16(a1, *(const short8*)&wr[32 + q * 8], acc, 0, 0, 0);
            acc = __builtin_amdgcn_mfma_f32_16x16x32_bf16(a2, *(const short8*)&wr[64 + q * 8], acc, 0, 0, 0);
            acc = __builtin_amdgcn_mfma_f32_16x16x32_bf16(a3, *(const short8*)&wr[96 + q * 8], acc, 0, 0, 0);
            float bias = ldf(bfn0, j, m);
            float sc = ldf(g0, j, m) * rsqrtf(ldf(rv0, j, m) + BN_EPS);
            float sh = ldf(b0, j, m) - ldf(rm0, j, m) * sc;
#pragma unroll
            for (int r = 0; r < 4; r++) {
                int row = w * 16 + q * 4 + r;
                xs[row][j] = f2bf(fmaxf(acc[r] + bias, 0.f) * sc + sh);
            }
        }
    }
    __syncthreads();
    {
        const u16* ar = &xs[w * 16 + nidx][0];
        short8 a0 = *(const short8*)&ar[q * 8];
        short8 a1 = *(const short8*)&ar[32 + q * 8];
        short8 a2 = *(const short8*)&ar[64 + q * 8];
        short8 a3 = *(const short8*)&ar[96 + q * 8];
#pragma unroll
        for (int jt = 0; jt < 4; jt++) {
            int j = jt * 16 + nidx;
            const u16* wr = Wn1c + j * 128;
            floatx4 acc = {0.f, 0.f, 0.f, 0.f};
            acc = __builtin_amdgcn_mfma_f32_16x16x32_bf16(a0, *(const short8*)&wr[q * 8], acc, 0, 0, 0);
            acc = __builtin_amdgcn_mfma_f32_16x16x32_bf16(a1, *(const short8*)&wr[32 + q * 8], acc, 0, 0, 0);
            acc = __builtin_amdgcn_mfma_f32_16x16x32_bf16(a2, *(const short8*)&wr[64 + q * 8], acc, 0, 0, 0);
            acc = __builtin_amdgcn_mfma_f32_16x16x32_bf16(a3, *(const short8*)&wr[96 + q * 8], acc, 0, 0, 0);
#pragma unroll
            for (int r = 0; r < 4; r++) {
                int row = w * 16 + q * 4 + r;
                int n = n0 + row;
                if (n < NN) n1l1[n * 64 + j] = f2bf(fmaxf(acc[r], 0.f));
            }
        }
    }
}

// K5v7: r6 structure, single change: per-tile __syncthreads() -> LDS_BARRIER()
// (lgkmcnt-only drain). The per-tile global atomics stay in flight across tiles
// instead of completing on the barrier critical path.
__global__ __launch_bounds__(256) void k_edge7(
    const int* __restrict__ ei, const void* __restrict__ ea, const u16* __restrict__ n1l0,
    const u16* __restrict__ Wfe0c, const void* __restrict__ bfe0,
    const float* __restrict__ PN, const u16* __restrict__ We1c,
    float* __restrict__ agg, const int* __restrict__ mf) {
    int m = mf[0];
    __shared__ __align__(16) u16 h1s[2][16][136];
    int t = threadIdx.x;
    int lane = t & 63, w = t >> 6, q = lane >> 4, nidx = lane & 15;
    // ---- per-block register hoists ----
    short8 wA[2][2];           // GEMM1 A-frags (swapped): W row = jt*16+nidx
    float bias[2][4], Pv[2][4], Nv[2][4];
#pragma unroll
    for (int jj = 0; jj < 2; jj++) {
        int jt = 2 * w + jj;
        const u16* wr = Wfe0c + (jt * 16 + nidx) * 128;
        wA[jj][0] = *(const short8*)&wr[q * 8];
        wA[jj][1] = *(const short8*)&wr[32 + q * 8];
#pragma unroll
        for (int r = 0; r < 4; r++) {
            int ch = jt * 16 + q * 4 + r;
            bias[jj][r] = ldf(bfe0, ch, m);
            Pv[jj][r] = PN[ch];
            Nv[jj][r] = PN[128 + ch];
        }
    }
    int c2 = w * 16 + nidx;
    const u16* wr2 = We1c + c2 * 128;
    short8 wB0 = *(const short8*)&wr2[q * 8];
    short8 wB1 = *(const short8*)&wr2[32 + q * 8];
    short8 wB2 = *(const short8*)&wr2[64 + q * 8];
    short8 wB3 = *(const short8*)&wr2[96 + q * 8];

    int e0 = blockIdx.x * (16 * TPB);
    // ---- prologue: tile 0 loads ----
    int eb = e0 + nidx;
    int sv = ei[eb];
    int dv = ei[NE + eb];
    float av = ldf(ea, eb, m);
    const u16* srow = n1l0 + (size_t)sv * 64;
    const u16* drow = n1l0 + (size_t)dv * 64;
    short8 as0 = *(const short8*)&srow[q * 8];
    short8 as1 = *(const short8*)&srow[32 + q * 8];
    short8 ad0 = *(const short8*)&drow[q * 8];
    short8 ad1 = *(const short8*)&drow[32 + q * 8];

    for (int tile = 0; tile < TPB; tile++) {
        short8 cs0 = as0, cs1 = as1, cd0 = ad0, cd1 = ad1;
        int curd = dv;
        float cura = av;
        if (tile + 1 < TPB) {   // issue next tile's loads early (hidden under GEMMs)
            int en = e0 + (tile + 1) * 16 + nidx;
            sv = ei[en];
            dv = ei[NE + en];
            av = ldf(ea, en, m);
            srow = n1l0 + (size_t)sv * 64;
            drow = n1l0 + (size_t)dv * 64;
            as0 = *(const short8*)&srow[q * 8];
            as1 = *(const short8*)&srow[32 + q * 8];
            ad0 = *(const short8*)&drow[q * 8];
            ad1 = *(const short8*)&drow[32 + q * 8];
        }
        u16* hp = &h1s[tile & 1][0][0];
        // GEMM1 (swapped): channels jt*16+q*4+r for edge nidx; src/dst chains split for ILP
#pragma unroll
        for (int jj = 0; jj < 2; jj++) {
            floatx4 accS = {0.f, 0.f, 0.f, 0.f};
            floatx4 accD = {0.f, 0.f, 0.f, 0.f};
            accS = __builtin_amdgcn_mfma_f32_16x16x32_bf16(wA[jj][0], cs0, accS, 0, 0, 0);
            accD = __builtin_amdgcn_mfma_f32_16x16x32_bf16(wA[jj][0], cd0, accD, 0, 0, 0);
            accS = __builtin_amdgcn_mfma_f32_16x16x32_bf16(wA[jj][1], cs1, accS, 0, 0, 0);
            accD = __builtin_amdgcn_mfma_f32_16x16x32_bf16(wA[jj][1], cd1, accD, 0, 0, 0);
            float v0 = fmaxf(accS[0] + accD[0] + bias[jj][0] + cura * (cura > 0.f ? Pv[jj][0] : Nv[jj][0]), 0.f);
            float v1 = fmaxf(accS[1] + accD[1] + bias[jj][1] + cura * (cura > 0.f ? Pv[jj][1] : Nv[jj][1]), 0.f);
            float v2 = fmaxf(accS[2] + accD[2] + bias[jj][2] + cura * (cura > 0.f ? Pv[jj][2] : Nv[jj][2]), 0.f);
            float v3 = fmaxf(accS[3] + accD[3] + bias[jj][3] + cura * (cura > 0.f ? Pv[jj][3] : Nv[jj][3]), 0.f);
            unsigned lo = (unsigned)f2bf(v0) | ((unsigned)f2bf(v1) << 16);
            unsigned hi = (unsigned)f2bf(v2) | ((unsigned)f2bf(v3) << 16);
            uint2 pk; pk.x = lo; pk.y = hi;
            *(uint2*)&hp[nidx * 136 + w * 32 + jj * 16 + q * 4] = pk;
        }
        LDS_BARRIER();
        // GEMM2: e1' = relu(h1 @ We1^T); D row=q*4+r=edge, col=nidx -> channel c2
        const u16* arow = &h1s[tile & 1][nidx][0];
        floatx4 accA = {0.f, 0.f, 0.f, 0.f};
        floatx4 accB = {0.f, 0.f, 0.f, 0.f};
        accA = __builtin_amdgcn_mfma_f32_16x16x32_bf16(*(const short8*)&arow[q * 8], wB0, accA, 0, 0, 0);
        accB = __builtin_amdgcn_mfma_f32_16x16x32_bf16(*(const short8*)&arow[32 + q * 8], wB1, accB, 0, 0, 0);
        accA = __builtin_amdgcn_mfma_f32_16x16x32_bf16(*(const short8*)&arow[64 + q * 8], wB2, accA, 0, 0, 0);
        accB = __builtin_amdgcn_mfma_f32_16x16x32_bf16(*(const short8*)&arow[96 + q * 8], wB3, accB, 0, 0, 0);
        // dsts of my 4 edges (q*4+r) via shfl of the tile's per-lane dst
        int d0 = __shfl(curd, q * 4 + 0);
        int d1 = __shfl(curd, q * 4 + 1);
        int d2 = __shfl(curd, q * 4 + 2);
        int d3 = __shfl(curd, q * 4 + 3);
        atomicAdd(agg + (size_t)d0 * 64 + c2, fmaxf(accA[0] + accB[0], 0.f));
        atomicAdd(agg + (size_t)d1 * 64 + c2, fmaxf(accA[1] + accB[1], 0.f));
        atomicAdd(agg + (size_t)d2 * 64 + c2, fmaxf(accA[2] + accB[2], 0.f));
        atomicAdd(agg + (size_t)d3 * 64 + c2, fmaxf(accA[3] + accB[3], 0.f));
        // LDS_BARRIER above also orders write(t+2) vs read(t) via the double buffer
    }
}

// K6: node MLP l1 + BN -> d_out. MFMA, 64 nodes/block.
__global__ __launch_bounds__(256) void k_node_l1(
    const u16* __restrict__ n1l1, const float* __restrict__ agg,
    const u16* __restrict__ Wfn1c, const void* __restrict__ bfn1,
    const void* __restrict__ g1, const void* __restrict__ b1,
    const void* __restrict__ rm1, const void* __restrict__ rv1,
    void* __restrict__ out, const int* __restrict__ mf) {
    int m = mf[0];
    __shared__ __align__(16) u16 fs[64][136];
    int t = threadIdx.x;
    int n0 = blockIdx.x * 64;
    {
        int col = t & 127;
        int rbase = t >> 7;
#pragma unroll
        for (int i = 0; i < 32; i++) {
            int row = rbase + 2 * i;
            int n = n0 + row;
            float v = 0.f;
            if (n < NN) v = (col < 64) ? agg[n * 64 + col] : bfu(n1l1[n * 64 + col - 64]);
            fs[row][col] = f2bf(v);
        }
    }
    __syncthreads();
    int lane = t & 63, w = t >> 6, q = lane >> 4, nidx = lane & 15;
    const u16* ar = &fs[w * 16 + nidx][0];
    short8 a0 = *(const short8*)&ar[q * 8];
    short8 a1 = *(const short8*)&ar[32 + q * 8];
    short8 a2 = *(const short8*)&ar[64 + q * 8];
    short8 a3 = *(const short8*)&ar[96 + q * 8];
#pragma unroll
    for (int jt = 0; jt < 8; jt++) {
        int j = jt * 16 + nidx;
        const u16* wr = Wfn1c + j * 128;
        floatx4 acc = {0.f, 0.f, 0.f, 0.f};
        acc = __builtin_amdgcn_mfma_f32_16x16x32_bf16(a0, *(const short8*)&wr[q * 8], acc, 0, 0, 0);
        acc = __builtin_amdgcn_mfma_f32_16x16x32_bf16(a1, *(const short8*)&wr[32 + q * 8], acc, 0, 0, 0);
        acc = __builtin_amdgcn_mfma_f32_16x16x32_bf16(a2, *(const short8*)&wr[64 + q * 8], acc, 0, 0, 0);
        acc = __builtin_amdgcn_mfma_f32_16x16x32_bf16(a3, *(const short8*)&wr[96 + q * 8], acc, 0, 0, 0);
        float bias = ldf(bfn1, j, m);
        float sc = ldf(g1, j, m) * rsqrtf(ldf(rv1, j, m) + BN_EPS);
        float sh = ldf(b1, j, m) - ldf(rm1, j, m) * sc;
#pragma unroll
        for (int r = 0; r < 4; r++) {
            int row = w * 16 + q * 4 + r;
            int n = n0 + row;
            if (n < NN) {
                float v = fmaxf(acc[r] + bias, 0.f) * sc + sh;
                if (m) ((float*)out)[n * 128 + j] = v;
                else   ((u16*)out)[n * 128 + j] = f2bf(v);
            }
        }
    }
}

extern "C" void kernel_launch(void* const* d_in, const int* in_sizes, int n_in,
                              void* d_out, int out_size, void* d_ws, size_t ws_size,
                              hipStream_t stream) {
    const void* x    = d_in[0];
    const void* ea   = d_in[1];
    const int*  ei   = (const int*)d_in[2];
    const void* Wn0  = d_in[3];
    const void* We0  = d_in[4];
    const void* Wfn0 = d_in[5];
    const void* bfn0 = d_in[6];
    const void* Wfe0 = d_in[7];
    const void* bfe0 = d_in[8];
    const void* g0   = d_in[9];
    const void* b0   = d_in[10];
    const void* rm0  = d_in[11];
    const void* rv0  = d_in[12];
    const void* Wn1  = d_in[13];
    const void* We1  = d_in[14];
    const void* Wfn1 = d_in[15];
    const void* bfn1 = d_in[16];
    // d_in[17]/d_in[18] (l1_Wfe/l1_bfe): dead — layer-1 edge output discarded
    const void* g1   = d_in[19];
    const void* b1   = d_in[20];
    const void* rm1  = d_in[21];
    const void* rv1  = d_in[22];

    float* wsf    = (float*)d_ws;
    float* agg    = wsf;                          // 3,200,000 f32
    u16*   n1l0   = (u16*)(wsf + 3200000);        // 3.2M u16
    u16*   n1l1   = (u16*)(wsf + 4800000);        // 3.2M u16
    float* sp     = wsf + 6400000;                // 50,000
    float* sn     = wsf + 6450000;                // 50,000
    float* PN     = wsf + 6500000;                // 256
    u16*   Wc     = (u16*)(wsf + 6500256);        // 65,536 u16 canonical weights
    int*   mode   = (int*)(wsf + 6533024);        // 1
    u16* Wfe0c = Wc;
    u16* We1c  = Wc + 16384;
    u16* Wfn0c = Wc + 24576;
    u16* Wn1c  = Wc + 40960;
    u16* Wfn1c = Wc + 49152;

    // Zero sp + sn (contiguous) and agg (atomic-accumulated).
    hipMemsetAsync(sp, 0, 100000 * sizeof(float), stream);
    hipMemsetAsync(agg, 0, 3200000 * sizeof(float), stream);

    k_cvtw<<<257, 256, 0, stream>>>((const u16*)x, Wfe0, We1, Wfn0, Wn1, Wfn1,
                                    We0, Wc, PN, mode);
    k_enc0h<<<9375, 256, 0, stream>>>(x, Wn0, n1l0, ei, ea, sp, sn, mode);
    k_node_l0<<<782, 256, 0, stream>>>(n1l0, sp, sn, We0, Wfn0c, bfn0,
                                       g0, b0, rm0, rv0, Wn1c, n1l1, mode);
    k_edge7<<<NE / (16 * TPB), 256, 0, stream>>>(ei, ea, n1l0, Wfe0c, bfe0, PN, We1c, agg, mode);
    k_node_l1<<<782, 256, 0, stream>>>(n1l1, agg, Wfn1c, bfn1,
                                       g1, b1, rm1, rv1, d_out, mode);
}